// Round 1
// baseline (1204.938 us; speedup 1.0000x reference)
//
#include <hip/hip_runtime.h>
#include <hip/hip_bf16.h>

typedef short bf16x8 __attribute__((ext_vector_type(8)));
typedef float f32x4 __attribute__((ext_vector_type(4)));
typedef unsigned short u16;

__device__ __forceinline__ u16 f2bf(float v) {
    union { __hip_bfloat16 h; u16 u; } cv;
    cv.h = __float2bfloat16(v);
    return cv.u;
}

// ---------------- prep kernels ----------------
__global__ void prep_w1(const float* __restrict__ w, u16* __restrict__ o) {
    int idx = blockIdx.x * 256 + threadIdx.x;
    if (idx >= 25 * 512 * 512) return;
    int ic = idx & 511, rest = idx >> 9;
    int oc = rest & 511, tap = rest >> 9;
    int kh = tap / 5, kw = tap % 5;
    float v = w[(((size_t)oc * 512 + ic) * 5 + kh) * 5 + kw];
    o[idx] = f2bf(v);
}

__global__ void prep_w2(const float* __restrict__ w, u16* __restrict__ o) {
    int idx = blockIdx.x * 256 + threadIdx.x;
    if (idx >= 15 * 512 * 512) return;
    int ic = idx & 511, rest = idx >> 9;
    int oc = rest & 511, tap = rest >> 9;
    int kh = tap / 3, kw = tap % 3;
    float v = w[(((size_t)oc * 512 + ic) * 5 + kh) * 3 + kw];
    o[idx] = f2bf(v);
}

__global__ void prep_bn(const float* __restrict__ g, const float* __restrict__ b,
                        const float* __restrict__ m, const float* __restrict__ v,
                        float* __restrict__ scale, float* __restrict__ shift) {
    int i = blockIdx.x * 256 + threadIdx.x;
    if (i >= 512) return;
    float s = g[i] * rsqrtf(v[i] + 1e-5f);
    scale[i] = s;
    shift[i] = b[i] - m[i] * s;
}

// zero the H-pad rows {0,1,1026,1027} of gathered [8][1028][12][512] bf16
__global__ void zero_gpads(u16* __restrict__ g) {
    int idx = blockIdx.x * 256 + threadIdx.x;   // int4 units
    if (idx >= 8 * 4 * 768) return;             // 768 int4 per (b,row)
    int part = idx % 768;
    int combo = idx / 768;
    int b = combo >> 2, r4 = combo & 3;
    int row = (r4 < 2) ? r4 : (1024 + r4);      // 0,1,1026,1027
    u16* p = g + ((size_t)(b * 1028 + row) * 12 * 512) + (size_t)part * 8;
    *(int4*)p = int4{0, 0, 0, 0};
}

// ---------------- scores + top-k + gather ----------------
__global__ __launch_bounds__(256) void gather_topk(const float* __restrict__ x,
                                                   u16* __restrict__ g) {
    int bt = blockIdx.x;
    int b = bt >> 10, t = bt & 1023;
    const float* xb = x + (size_t)b * 1024 * 512;
    const float* xt = xb + (size_t)t * 512;
    __shared__ float xts[512];
    __shared__ float sc[23];
    __shared__ int sel[12];
    int tid = threadIdx.x;
    for (int i = tid; i < 512; i += 256) xts[i] = xt[i];
    __syncthreads();
    int j0 = t - 11; if (j0 < 0) j0 = 0;
    int j1 = t + 11; if (j1 > 1023) j1 = 1023;
    int C = j1 - j0 + 1;                        // 12..23, always >= 12
    int wave = tid >> 6, lane = tid & 63;
    for (int c = wave; c < C; c += 4) {
        const float* xj = xb + (size_t)(j0 + c) * 512;
        double s = 0.0;
        #pragma unroll
        for (int e = 0; e < 8; ++e) {
            int d = lane * 8 + e;
            s += (double)xj[d] * (double)xts[d];
        }
        #pragma unroll
        for (int off = 32; off; off >>= 1) s += __shfl_xor(s, off, 64);
        if (lane == 0) sc[c] = (float)(s / 22.627416997969522);  // / sqrt(512)
    }
    __syncthreads();
    if (tid == 0) {
        int cnt = 0;
        for (int c = 0; c < C; ++c) {
            float v = sc[c];
            int r = 0;
            for (int k = 0; k < C; ++k) {
                float u = sc[k];
                r += (u > v) || (u == v && k < c);   // stable: lower index wins ties
            }
            if (r < 12) sel[cnt++] = j0 + c;         // ascending j == sorted ids
        }
    }
    __syncthreads();
    u16* dst = g + ((size_t)(b * 1028 + t + 2) * 12) * 512;
    for (int i = tid; i < 12 * 512; i += 256) {
        int s_ = i >> 9, d = i & 511;
        dst[i] = f2bf(xb[(size_t)sel[s_] * 512 + d]);
    }
}

// ---------------- implicit-GEMM conv + bias + BN + ReLU ----------------
// A: [b][outH+4][IN_W][512] bf16 (H zero-padded by 2 each side)
// Wb: [KH*KW][oc 512][ic 512] bf16
// out: OCMAJOR ? fp32 [b][512][outH][OW] : bf16 [b][outH][OW][512]
template <int IN_W, int LOG_OW, int KH, int KW, int TH, int HTB, bool OCMAJOR>
__global__ __launch_bounds__(512) void conv_bn_relu(
    const u16* __restrict__ A, const u16* __restrict__ Wb,
    const float* __restrict__ bias, const float* __restrict__ bnsc,
    const float* __restrict__ bnsh, void* __restrict__ outp) {
    constexpr int OW = 1 << LOG_OW;
    constexpr int HALO = TH + KH - 1;
    constexpr int AROWS = HALO * IN_W;
    constexpr int KC = 64, KP = 72;
    constexpr int OUTH = TH * HTB;
    __shared__ u16 As[AROWS][KP];
    __shared__ u16 Ws[256][KP];

    int tid = threadIdx.x;
    int bid = blockIdx.x;
    int n0 = (bid & 1) * 256;
    int mt = bid >> 1;
    int b = mt / HTB;
    int h0 = (mt % HTB) * TH;

    int lane = tid & 63;
    int wv = tid >> 6;
    int wm = wv >> 2, wn = wv & 3;
    int l15 = lane & 15, grp = lane >> 4;

    int apos[4];
    #pragma unroll
    for (int mf = 0; mf < 4; ++mf) {
        int pos = wm * 64 + mf * 16 + l15;
        apos[mf] = (pos >> LOG_OW) * IN_W + (pos & (OW - 1));
    }
    int bocl[4];
    #pragma unroll
    for (int nf = 0; nf < 4; ++nf) bocl[nf] = wn * 64 + nf * 16 + l15;

    f32x4 acc[4][4];
    #pragma unroll
    for (int i = 0; i < 4; ++i)
        #pragma unroll
        for (int j = 0; j < 4; ++j) acc[i][j] = f32x4{0.f, 0.f, 0.f, 0.f};

    const size_t abase = ((size_t)b * (OUTH + KH - 1) + h0) * IN_W * 512;

    #pragma unroll 1
    for (int ic0 = 0; ic0 < 512; ic0 += KC) {
        __syncthreads();   // protect As (and last tap's Ws) from prior reads
        constexpr int CHA = AROWS * 8;
        for (int c = tid; c < CHA; c += 512) {
            int rowIdx = c >> 3, part = c & 7;
            int r = rowIdx / IN_W, w = rowIdx - r * IN_W;
            const int4 v = *(const int4*)(A + abase + ((size_t)r * IN_W + w) * 512
                                          + ic0 + part * 8);
            *(int4*)&As[rowIdx][part * 8] = v;
        }
        #pragma unroll 1
        for (int tap = 0; tap < KH * KW; ++tap) {
            __syncthreads();   // waves done reading previous Ws (covers As on tap 0 too)
            const u16* wsrc = Wb + (size_t)tap * (512 * 512) + (size_t)n0 * 512 + ic0;
            #pragma unroll
            for (int c4 = 0; c4 < 4; ++c4) {
                int c = tid + c4 * 512;
                int ocl = c >> 3, part = c & 7;
                const int4 v = *(const int4*)(wsrc + (size_t)ocl * 512 + part * 8);
                *(int4*)&Ws[ocl][part * 8] = v;
            }
            __syncthreads();
            int kh = tap / KW, kw = tap % KW;
            int tapoff = kh * IN_W + kw;
            #pragma unroll
            for (int ks = 0; ks < 2; ++ks) {
                bf16x8 af[4], bfr[4];
                #pragma unroll
                for (int mf = 0; mf < 4; ++mf)
                    af[mf] = *(const bf16x8*)&As[apos[mf] + tapoff][ks * 32 + grp * 8];
                #pragma unroll
                for (int nf = 0; nf < 4; ++nf)
                    bfr[nf] = *(const bf16x8*)&Ws[bocl[nf]][ks * 32 + grp * 8];
                #pragma unroll
                for (int mf = 0; mf < 4; ++mf)
                    #pragma unroll
                    for (int nf = 0; nf < 4; ++nf)
                        acc[mf][nf] = __builtin_amdgcn_mfma_f32_16x16x32_bf16(
                            af[mf], bfr[nf], acc[mf][nf], 0, 0, 0);
            }
        }
    }

    // epilogue: y = relu(conv*sc + (bias*sc + sh))
    #pragma unroll
    for (int nf = 0; nf < 4; ++nf) {
        int oc = n0 + wn * 64 + nf * 16 + l15;
        float scv = bnsc[oc], shv = bnsh[oc], bi = bias[oc];
        float shh = fmaf(bi, scv, shv);
        #pragma unroll
        for (int mf = 0; mf < 4; ++mf) {
            #pragma unroll
            for (int r = 0; r < 4; ++r) {
                int pos = wm * 64 + mf * 16 + grp * 4 + r;   // C/D: row=(lane>>4)*4+reg
                int lh = pos >> LOG_OW, lw = pos & (OW - 1);
                int h = h0 + lh;
                float v = fmaxf(fmaf(acc[mf][nf][r], scv, shh), 0.f);
                if (OCMAJOR) {
                    float* o = (float*)outp;
                    o[(((size_t)b * 512 + oc) * OUTH + h) * OW + lw] = v;
                } else {
                    u16* o = (u16*)outp;
                    o[(((size_t)b * OUTH + h) * OW + lw) * 512 + oc] = f2bf(v);
                }
            }
        }
    }
}

// ---------------- pools ----------------
// in: [8][1024][8][512] bf16 (relu'd, >=0) -> out: [8][516][4][512] bf16, pads zeroed
__global__ void pool1(const u16* __restrict__ in, u16* __restrict__ out) {
    int idx = blockIdx.x * 256 + threadIdx.x;
    if (idx >= 8 * 516 * 4 * 64) return;
    int icv = idx & 63, rest = idx >> 6;
    int w = rest & 3; rest >>= 2;
    int hp = rest % 516, b = rest / 516;
    u16* op = out + (((size_t)(b * 516 + hp) * 4 + w) * 512 + icv * 8);
    if (hp < 2 || hp >= 514) { *(int4*)op = int4{0, 0, 0, 0}; return; }
    int h = (hp - 2) * 2, wi = w * 2;
    const u16* p0 = in + (((size_t)(b * 1024 + h) * 8 + wi) * 512 + icv * 8);
    const u16* a = p0;
    const u16* bq = p0 + 512;
    const u16* c = p0 + 8 * 512;
    const u16* d = p0 + 8 * 512 + 512;
    u16 r[8];
    #pragma unroll
    for (int e = 0; e < 8; ++e) {
        u16 m1 = a[e] > bq[e] ? a[e] : bq[e];     // bf16 >=0: bit pattern monotone
        u16 m2 = c[e] > d[e] ? c[e] : d[e];
        r[e] = m1 > m2 ? m1 : m2;
    }
    *(int4*)op = *(const int4*)r;
}

// in: fp32 [8][512][512][2] (>=0) -> d_out fp32 [8][512][256]
__global__ void pool2(const float* __restrict__ in, float* __restrict__ out) {
    int idx = blockIdx.x * 256 + threadIdx.x;
    if (idx >= 8 * 512 * 256) return;
    const float* p = in + (size_t)idx * 4;
    out[idx] = fmaxf(fmaxf(p[0], p[1]), fmaxf(p[2], p[3]));
}

// ---------------- launch ----------------
extern "C" void kernel_launch(void* const* d_in, const int* in_sizes, int n_in,
                              void* d_out, int out_size, void* d_ws, size_t ws_size,
                              hipStream_t stream) {
    const float* x  = (const float*)d_in[0];
    const float* w1 = (const float*)d_in[1];
    const float* b1 = (const float*)d_in[2];
    const float* g1 = (const float*)d_in[3];
    const float* be1 = (const float*)d_in[4];
    const float* m1 = (const float*)d_in[5];
    const float* v1 = (const float*)d_in[6];
    const float* w2 = (const float*)d_in[7];
    const float* b2 = (const float*)d_in[8];
    const float* g2 = (const float*)d_in[9];
    const float* be2 = (const float*)d_in[10];
    const float* m2 = (const float*)d_in[11];
    const float* v2 = (const float*)d_in[12];
    float* out = (float*)d_out;

    char* ws = (char*)d_ws;
    u16* gathered  = (u16*)(ws);                   // 101,056,512 B
    u16* w1b       = (u16*)(ws + 101056512);       // 13,107,200 B
    u16* w2b       = (u16*)(ws + 114163712);       //  7,864,320 B
    float* bn1s    = (float*)(ws + 122028032);
    float* bn1t    = bn1s + 512;
    float* bn2s    = bn1s + 1024;
    float* bn2t    = bn1s + 1536;
    u16* conv1out  = (u16*)(ws + 122036224);       // 67,108,864 B
    u16* pooled1   = (u16*)(ws);                   // aliases gathered (dead by then)
    float* conv2out = (float*)(ws + 16908288);     // 16,777,216 B (inside gathered region)

    prep_w1<<<(25 * 512 * 512 + 255) / 256, 256, 0, stream>>>(w1, w1b);
    prep_w2<<<(15 * 512 * 512 + 255) / 256, 256, 0, stream>>>(w2, w2b);
    prep_bn<<<2, 256, 0, stream>>>(g1, be1, m1, v1, bn1s, bn1t);
    prep_bn<<<2, 256, 0, stream>>>(g2, be2, m2, v2, bn2s, bn2t);
    zero_gpads<<<(8 * 4 * 768 + 255) / 256, 256, 0, stream>>>(gathered);
    gather_topk<<<8192, 256, 0, stream>>>(x, gathered);

    // conv1: IN_W=12, OW=8, 5x5, TH=16, 64 h-tiles/b -> grid 8*64*2
    conv_bn_relu<12, 3, 5, 5, 16, 64, false><<<1024, 512, 0, stream>>>(
        gathered, w1b, b1, bn1s, bn1t, conv1out);
    pool1<<<(8 * 516 * 4 * 64 + 255) / 256, 256, 0, stream>>>(conv1out, pooled1);
    // conv2: IN_W=4, OW=2, 5x3, TH=64, 8 h-tiles/b -> grid 8*8*2
    conv_bn_relu<4, 1, 5, 3, 64, 8, true><<<128, 512, 0, stream>>>(
        pooled1, w2b, b2, bn2s, bn2t, conv2out);
    pool2<<<(8 * 512 * 256 + 255) / 256, 256, 0, stream>>>(conv2out, out);
}